// Round 8
// baseline (436.439 us; speedup 1.0000x reference)
//
#include <hip/hip_runtime.h>
#include <cstdint>

typedef __bf16 bf16_t;
typedef __attribute__((ext_vector_type(8))) __bf16 bf16x8;
typedef __attribute__((ext_vector_type(4))) __bf16 bf16x4;
typedef __attribute__((ext_vector_type(4))) float f32x4;

#define MFMA16(a, b, c) __builtin_amdgcn_mfma_f32_16x16x32_bf16((a), (b), (c), 0, 0, 0)

// async global->LDS, 16B per lane. LDS dest must be wave-uniform base; HW writes lane i at base + i*16.
__device__ inline void gll16(const bf16_t* g, bf16_t* lds) {
    __builtin_amdgcn_global_load_lds(
        (const __attribute__((address_space(1))) uint32_t*)g,
        (__attribute__((address_space(3))) uint32_t*)lds, 16, 0, 0);
}

// fast GELU: tanh form, exp2-domain. max dev from exact erf-GELU ~5e-4.
__device__ inline float gelu_f(float v) {
    const float u = v + 0.044715f * v * v * v;
    return v / (1.0f + exp2f(-2.3022038f * u));
}

// ---------------- fp32 -> bf16 convert, all 4 weights in one launch ----------------
__global__ __launch_bounds__(256) void cvt4_kernel(const float* __restrict__ s0, bf16_t* __restrict__ d0,
                                                   const float* __restrict__ s1, bf16_t* __restrict__ d1,
                                                   const float* __restrict__ s2, bf16_t* __restrict__ d2,
                                                   const float* __restrict__ s3, bf16_t* __restrict__ d3) {
    const int blk = blockIdx.x;
    const float* s; bf16_t* d; int base;
    if (blk < 864)       { s = s0; d = d0; base = blk; }
    else if (blk < 1152) { s = s1; d = d1; base = blk - 864; }
    else if (blk < 2304) { s = s2; d = d2; base = blk - 1152; }
    else                 { s = s3; d = d3; base = blk - 2304; }
    const int i = (base * 256 + threadIdx.x) * 8;
    const float4* sp = (const float4*)(s + i);
    float4 a = sp[0], b = sp[1];
    bf16x8 o;
    o[0] = (bf16_t)a.x; o[1] = (bf16_t)a.y; o[2] = (bf16_t)a.z; o[3] = (bf16_t)a.w;
    o[4] = (bf16_t)b.x; o[5] = (bf16_t)b.y; o[6] = (bf16_t)b.z; o[7] = (bf16_t)b.w;
    *(bf16x8*)(d + i) = o;
}

// ---------------- LayerNorm: wave per row (768 cols), fp32 in -> bf16 out ----------------
__global__ __launch_bounds__(256) void ln_kernel(const float* __restrict__ x,
                                                 const float* __restrict__ gw,
                                                 const float* __restrict__ bw,
                                                 bf16_t* __restrict__ out) {
    const int row  = blockIdx.x * 4 + (threadIdx.x >> 6);
    const int lane = threadIdx.x & 63;
    const float4* xr = (const float4*)(x + (long)row * 768);
    float4 v[3];
    float s = 0.f, q = 0.f;
#pragma unroll
    for (int j = 0; j < 3; ++j) {
        v[j] = xr[j * 64 + lane];
        s += v[j].x + v[j].y + v[j].z + v[j].w;
        q += v[j].x * v[j].x + v[j].y * v[j].y + v[j].z * v[j].z + v[j].w * v[j].w;
    }
#pragma unroll
    for (int off = 32; off > 0; off >>= 1) {
        s += __shfl_xor(s, off);
        q += __shfl_xor(q, off);
    }
    const float mu = s * (1.0f / 768.0f);
    const float rs = rsqrtf(q * (1.0f / 768.0f) - mu * mu + 1e-5f);
#pragma unroll
    for (int j = 0; j < 3; ++j) {
        float4 g4 = ((const float4*)gw)[j * 64 + lane];
        float4 b4 = ((const float4*)bw)[j * 64 + lane];
        bf16x4 o;
        o[0] = (bf16_t)((v[j].x - mu) * rs * g4.x + b4.x);
        o[1] = (bf16_t)((v[j].y - mu) * rs * g4.y + b4.y);
        o[2] = (bf16_t)((v[j].z - mu) * rs * g4.z + b4.z);
        o[3] = (bf16_t)((v[j].w - mu) * rs * g4.w + b4.w);
        *(bf16x4*)(out + (long)row * 768 + (j * 64 + lane) * 4) = o;
    }
}

// ---------------- GEMM 128x128, XCD-swizzled 1D grid ----------------
// id -> xcd = id&7, s = id>>3; tn = (s%NC)*128, tm = (xcd*RPX + s/NC)*128.
// MODE 0: QKV split-scatter: q->outb[bh][n][64], k->o1[bh][n][64], v->o2[bh][64][n] (transposed).
//         q/k epilogue goes through per-wave LDS transpose -> bf16x8 stores.
// MODE 2: out_bf16 = gelu(acc + bias)  (fc1), LDS-transpose epilogue -> bf16x8 stores.
template <int MODE, int NC, int RPX>
__global__ __launch_bounds__(256) void gemm_bt(const bf16_t* __restrict__ A,
                                               const bf16_t* __restrict__ Bw,
                                               const float* __restrict__ bias,
                                               bf16_t* __restrict__ outb,
                                               bf16_t* __restrict__ o1,
                                               bf16_t* __restrict__ o2,
                                               int Nn, int K) {
    __shared__ __align__(16) bf16_t As[128 * 32];
    __shared__ __align__(16) bf16_t Bs[128 * 32];
    __shared__ __align__(16) bf16_t Ts[4 * 16 * 72];   // per-wave transpose slab
    const int id = blockIdx.x;
    const int xcd = id & 7, sblk = id >> 3;
    const int tn = (sblk % NC) * 128;
    const int tm = (xcd * RPX + sblk / NC) * 128;
    const int w = threadIdx.x >> 6, l = threadIdx.x & 63;
    const int quad = l >> 4, r16 = l & 15;
    const int wm = (w >> 1) * 64, wn = (w & 1) * 64;
    f32x4 acc[4][4] = {};
    const bf16_t* ga = A  + (long)(tm + w * 32 + (l >> 2)) * K + (l & 3) * 8;
    const bf16_t* gb = Bw + (long)(tn + w * 32 + (l >> 2)) * K + (l & 3) * 8;
    bf16_t* la = As + w * 1024;
    bf16_t* lb = Bs + w * 1024;

    for (int k0 = 0; k0 < K; k0 += 32) {
        gll16(ga + k0,            la);
        gll16(ga + 16 * K + k0,   la + 512);
        gll16(gb + k0,            lb);
        gll16(gb + 16 * K + k0,   lb + 512);
        __syncthreads();
        bf16x8 af[4], bfr[4];
#pragma unroll
        for (int i = 0; i < 4; ++i) {
            af[i]  = *(const bf16x8*)&As[(wm + i * 16 + r16) * 32 + quad * 8];
            bfr[i] = *(const bf16x8*)&Bs[(wn + i * 16 + r16) * 32 + quad * 8];
        }
#pragma unroll
        for (int i = 0; i < 4; ++i)
#pragma unroll
            for (int j = 0; j < 4; ++j)
                acc[i][j] = MFMA16(af[i], bfr[j], acc[i][j]);
        __syncthreads();
    }

    bf16_t* tw = Ts + w * 16 * 72;
    if (MODE == 0) {
        const int sect = (tn + wn) / 768;               // wave-uniform (64-aligned)
        const int cwb  = tn + wn - sect * 768;
        const int h    = cwb >> 6;                      // wave-uniform head
        if (sect == 2) {
            // V: transposed layout [bh][64][n]; C-layout already packs 4 tokens -> b64 store
#pragma unroll
            for (int i = 0; i < 4; ++i) {
                const int r0 = tm + wm + i * 16 + quad * 4;
                const int b = r0 >> 10, n0 = r0 & 1023;
#pragma unroll
                for (int j = 0; j < 4; ++j) {
                    const int d = j * 16 + r16;
                    const float bv = bias[tn + wn + j * 16 + r16];
                    bf16x4 o;
#pragma unroll
                    for (int rr = 0; rr < 4; ++rr) o[rr] = (bf16_t)(acc[i][j][rr] + bv);
                    *(bf16x4*)(o2 + ((long)(b * 12 + h) * 64 + d) * 1024 + n0) = o;
                }
            }
        } else {
            bf16_t* dstbuf = (sect == 0 ? outb : o1);
#pragma unroll
            for (int i = 0; i < 4; ++i) {
#pragma unroll
                for (int j = 0; j < 4; ++j) {
                    const float bv = bias[tn + wn + j * 16 + r16];
#pragma unroll
                    for (int rr = 0; rr < 4; ++rr)
                        tw[(quad * 4 + rr) * 72 + j * 16 + r16] = (bf16_t)(acc[i][j][rr] + bv);
                }
                const int tok = tm + wm + i * 16 + (l >> 2);
                const int b = tok >> 10, n0 = tok & 1023;
                const long base = (long)(b * 12 + h) * 65536 + (long)n0 * 64;
#pragma unroll
                for (int it = 0; it < 2; ++it) {
                    bf16x8 vv = *(const bf16x8*)&tw[(l >> 2) * 72 + (l & 3) * 8 + it * 32];
                    *(bf16x8*)(dstbuf + base + (l & 3) * 8 + it * 32) = vv;
                }
            }
        }
    } else {
        // FC1: gelu -> LDS transpose -> bf16x8 row-major stores
#pragma unroll
        for (int i = 0; i < 4; ++i) {
#pragma unroll
            for (int j = 0; j < 4; ++j) {
                const float bv = bias[tn + wn + j * 16 + r16];
#pragma unroll
                for (int rr = 0; rr < 4; ++rr)
                    tw[(quad * 4 + rr) * 72 + j * 16 + r16] = (bf16_t)gelu_f(acc[i][j][rr] + bv);
            }
            const int grow = tm + wm + i * 16 + (l >> 2);
#pragma unroll
            for (int it = 0; it < 2; ++it) {
                bf16x8 vv = *(const bf16x8*)&tw[(l >> 2) * 72 + (l & 3) * 8 + it * 32];
                *(bf16x8*)(outb + (long)grow * Nn + tn + wn + (l & 3) * 8 + it * 32) = vv;
            }
        }
    }
}

// ---------------- GEMM 64x128 + residual (proj / fc2), XCD-swizzled 1D grid ----------------
// out_f32 = res + acc + bias; fp32 LDS-transpose epilogue -> float4 res-loads/stores.
__global__ __launch_bounds__(256) void gemm_res64(const bf16_t* __restrict__ A,
                                                  const bf16_t* __restrict__ Bw,
                                                  const float* __restrict__ bias,
                                                  const float* __restrict__ res,
                                                  float* __restrict__ outf,
                                                  int Nn, int K) {
    __shared__ __align__(16) bf16_t As[64 * 32];
    __shared__ __align__(16) bf16_t Bs[128 * 32];
    __shared__ __align__(16) float  Tf[4 * 16 * 68];   // per-wave fp32 transpose slab
    const int id = blockIdx.x;
    const int xcd = id & 7, sblk = id >> 3;
    const int tn = (sblk % 6) * 128;
    const int tm = (xcd * 16 + sblk / 6) * 64;
    const int w = threadIdx.x >> 6, l = threadIdx.x & 63;
    const int quad = l >> 4, r16 = l & 15;
    const int wm = (w >> 1) * 32, wn = (w & 1) * 64;
    f32x4 acc[2][4] = {};
    const bf16_t* ga = A  + (long)(tm + w * 16 + (l >> 2)) * K + (l & 3) * 8;
    const bf16_t* gb = Bw + (long)(tn + w * 32 + (l >> 2)) * K + (l & 3) * 8;
    bf16_t* la = As + w * 512;
    bf16_t* lb = Bs + w * 1024;

    for (int k0 = 0; k0 < K; k0 += 32) {
        gll16(ga + k0,            la);
        gll16(gb + k0,            lb);
        gll16(gb + 16 * K + k0,   lb + 512);
        __syncthreads();
        bf16x8 af[2], bfr[4];
#pragma unroll
        for (int i = 0; i < 2; ++i)
            af[i]  = *(const bf16x8*)&As[(wm + i * 16 + r16) * 32 + quad * 8];
#pragma unroll
        for (int j = 0; j < 4; ++j)
            bfr[j] = *(const bf16x8*)&Bs[(wn + j * 16 + r16) * 32 + quad * 8];
#pragma unroll
        for (int i = 0; i < 2; ++i)
#pragma unroll
            for (int j = 0; j < 4; ++j)
                acc[i][j] = MFMA16(af[i], bfr[j], acc[i][j]);
        __syncthreads();
    }
    float* tf = Tf + w * 16 * 68;
#pragma unroll
    for (int i = 0; i < 2; ++i) {
#pragma unroll
        for (int j = 0; j < 4; ++j) {
            const float bv = bias[tn + wn + j * 16 + r16];
#pragma unroll
            for (int rr = 0; rr < 4; ++rr)
                tf[(quad * 4 + rr) * 68 + j * 16 + r16] = acc[i][j][rr] + bv;
        }
        const int grow = tm + wm + i * 16 + (l >> 2);
#pragma unroll
        for (int it = 0; it < 4; ++it) {
            const int gcol = tn + wn + (l & 3) * 4 + it * 16;
            f32x4 vv = *(const f32x4*)&tf[(l >> 2) * 68 + (l & 3) * 4 + it * 16];
            const float4 rv = *(const float4*)(res + (long)grow * Nn + gcol);
            float4 ov;
            ov.x = rv.x + vv[0]; ov.y = rv.y + vv[1];
            ov.z = rv.z + vv[2]; ov.w = rv.w + vv[3];
            *(float4*)(outf + (long)grow * Nn + gcol) = ov;
        }
    }
}

// ---------------- Flash attention: K-tile 64, 5 blocks/CU ----------------
// grid (96 bh, 8 qt): linear id = qt*96+bh -> XCD = bh%8, K/V of one head L2-resident.
// block 256 = 4 waves; wave = 32 q-rows. LDS 27.6KB -> 5 blocks/CU (20 waves) vs 3 at K-tile 128.
// All LDS strides 72 elem = 36 dwords = 4 mod 32: b128 conflict-clean.
__global__ __launch_bounds__(256, 5) void attn_kernel(const bf16_t* __restrict__ qh,
                                                      const bf16_t* __restrict__ kh,
                                                      const bf16_t* __restrict__ vt,
                                                      bf16_t* __restrict__ ctx) {
    __shared__ __align__(16) bf16_t Ks[64 * 72];      // K-tile [key][d], pad 72
    __shared__ __align__(16) bf16_t Vt[64 * 72];      // V^T-tile [d][key], pad 72
    __shared__ __align__(16) bf16_t Ps[4 * 16 * 72];  // per-wave P buffer [16][72]
    const int w = threadIdx.x >> 6, l = threadIdx.x & 63;
    const int quad = l >> 4, r16 = l & 15;
    const int bh = blockIdx.x, qt = blockIdx.y;
    const bf16_t* qp = qh + (long)bh * 65536;
    const bf16_t* kp = kh + (long)bh * 65536;
    const bf16_t* vp = vt + (long)bh * 65536;
    const int q0 = qt * 128 + w * 32;
    const float SC = 0.18033688011f;  // (1/8) * log2(e): softmax in exp2 domain

    bf16x8 qf[2][2];
#pragma unroll
    for (int mt = 0; mt < 2; ++mt)
#pragma unroll
        for (int kq = 0; kq < 2; ++kq)
            qf[mt][kq] = *(const bf16x8*)(qp + (long)(q0 + mt * 16 + r16) * 64 + kq * 32 + quad * 8);

    float lsum[2][4] = {};   // per-lane partial row sums (16 lanes of a quad share rows)
    f32x4 oacc[2][4] = {};
    bf16_t* pw = Ps + w * 16 * 72;

    // staging indices (fixed per thread)
    const int srow = threadIdx.x >> 3, scg = threadIdx.x & 7;          // +c*32 rows
    for (int kt = 0; kt < 16; ++kt) {
        const int kb = kt * 64;
        // stage K-tile [64 key][64 d]: 512 x 16B, coalesced
#pragma unroll
        for (int c = 0; c < 2; ++c)
            *(bf16x8*)&Ks[(srow + c * 32) * 72 + scg * 8] =
                *(const bf16x8*)(kp + (long)(kb + srow + c * 32) * 64 + scg * 8);
        // stage V^T-tile [64 d][64 key]: 512 x 16B, coalesced
#pragma unroll
        for (int c = 0; c < 2; ++c)
            *(bf16x8*)&Vt[(srow + c * 32) * 72 + scg * 8] =
                *(const bf16x8*)(vp + (long)(srow + c * 32) * 1024 + kb + scg * 8);
        __syncthreads();

        bf16x8 kf[4][2];
#pragma unroll
        for (int nt = 0; nt < 4; ++nt) {
            kf[nt][0] = *(const bf16x8*)&Ks[(nt * 16 + r16) * 72 + quad * 8];
            kf[nt][1] = *(const bf16x8*)&Ks[(nt * 16 + r16) * 72 + 32 + quad * 8];
        }

#pragma unroll
        for (int mt = 0; mt < 2; ++mt) {
            f32x4 s[4] = {};
#pragma unroll
            for (int nt = 0; nt < 4; ++nt) {
                s[nt] = MFMA16(qf[mt][0], kf[nt][0], s[nt]);
                s[nt] = MFMA16(qf[mt][1], kf[nt][1], s[nt]);
            }
#pragma unroll
            for (int nt = 0; nt < 4; ++nt)
#pragma unroll
                for (int rr = 0; rr < 4; ++rr) {
                    const float p = exp2f(s[nt][rr] * SC);
                    lsum[mt][rr] += p;
                    pw[(quad * 4 + rr) * 72 + nt * 16 + r16] = (bf16_t)p;
                }
#pragma unroll
            for (int kc = 0; kc < 2; ++kc) {
                bf16x8 pf = *(const bf16x8*)&pw[r16 * 72 + kc * 32 + quad * 8];
#pragma unroll
                for (int dt = 0; dt < 4; ++dt) {
                    bf16x8 vf = *(const bf16x8*)&Vt[(dt * 16 + r16) * 72 + kc * 32 + quad * 8];
                    oacc[mt][dt] = MFMA16(pf, vf, oacc[mt][dt]);
                }
            }
        }
        __syncthreads();
    }
#pragma unroll
    for (int mt = 0; mt < 2; ++mt)
#pragma unroll
        for (int rr = 0; rr < 4; ++rr) {
#pragma unroll
            for (int off = 1; off < 16; off <<= 1)
                lsum[mt][rr] += __shfl_xor(lsum[mt][rr], off);
        }
    // epilogue: O/l -> per-wave LDS slab [16 tok][72] (reuse Ps) -> bf16x8 stores.
    // 16 tokens/tile, 4 lanes per token (row = l>>2, 16 elems/lane). same-wave DS ordering.
    const int b = bh / 12, h = bh % 12;
    const long tb = (long)b * 1024;
#pragma unroll
    for (int mt = 0; mt < 2; ++mt) {
#pragma unroll
        for (int dt = 0; dt < 4; ++dt)
#pragma unroll
            for (int rr = 0; rr < 4; ++rr)
                pw[(quad * 4 + rr) * 72 + dt * 16 + r16] =
                    (bf16_t)(oacc[mt][dt][rr] / lsum[mt][rr]);
        const int tok = q0 + mt * 16 + (l >> 2);
        const int off = (l & 3) * 16;
        bf16_t* dst = ctx + (tb + tok) * 768 + h * 64 + off;
        const bf16_t* src = &pw[(l >> 2) * 72 + off];
#pragma unroll
        for (int it = 0; it < 2; ++it)
            *(bf16x8*)(dst + it * 8) = *(const bf16x8*)(src + it * 8);
    }
}

// ---------------- launch ----------------
extern "C" void kernel_launch(void* const* d_in, const int* in_sizes, int n_in,
                              void* d_out, int out_size, void* d_ws, size_t ws_size,
                              hipStream_t stream) {
    const float* x      = (const float*)d_in[0];
    const float* ln1_g  = (const float*)d_in[1];
    const float* ln1_b  = (const float*)d_in[2];
    const float* qkv_w  = (const float*)d_in[3];
    const float* qkv_b  = (const float*)d_in[4];
    const float* proj_w = (const float*)d_in[5];
    const float* proj_b = (const float*)d_in[6];
    const float* ln2_g  = (const float*)d_in[7];
    const float* ln2_b  = (const float*)d_in[8];
    const float* fc1_w  = (const float*)d_in[9];
    const float* fc1_b  = (const float*)d_in[10];
    const float* fc2_w  = (const float*)d_in[11];
    const float* fc2_b  = (const float*)d_in[12];

    char* p = (char*)d_ws;
    bf16_t* wqkv  = (bf16_t*)p; p += (size_t)2304 * 768 * 2;
    bf16_t* wproj = (bf16_t*)p; p += (size_t)768 * 768 * 2;
    bf16_t* wfc1  = (bf16_t*)p; p += (size_t)3072 * 768 * 2;
    bf16_t* wfc2  = (bf16_t*)p; p += (size_t)768 * 3072 * 2;
    bf16_t* h1    = (bf16_t*)p; p += (size_t)8192 * 768 * 2;
    bf16_t* qhb   = (bf16_t*)p; p += (size_t)96 * 1024 * 64 * 2;
    bf16_t* khb   = (bf16_t*)p; p += (size_t)96 * 1024 * 64 * 2;
    bf16_t* vtb   = (bf16_t*)p; p += (size_t)96 * 64 * 1024 * 2;
    bf16_t* ctx   = (bf16_t*)p; p += (size_t)8192 * 768 * 2;
    float*  x2    = (float*)p;  p += (size_t)8192 * 768 * 4;
    bf16_t* h2    = (bf16_t*)p; p += (size_t)8192 * 768 * 2;
    bf16_t* a1    = (bf16_t*)p; p += (size_t)8192 * 3072 * 2;

    cvt4_kernel<<<3456, 256, 0, stream>>>(qkv_w, wqkv, proj_w, wproj, fc1_w, wfc1, fc2_w, wfc2);

    ln_kernel<<<2048, 256, 0, stream>>>(x, ln1_g, ln1_b, h1);
    gemm_bt<0, 18, 8><<<1152, 256, 0, stream>>>(h1, wqkv, qkv_b, qhb, khb, vtb, 2304, 768);
    attn_kernel<<<dim3(96, 8), 256, 0, stream>>>(qhb, khb, vtb, ctx);
    gemm_res64<<<768, 256, 0, stream>>>(ctx, wproj, proj_b, x, x2, 768, 768);
    ln_kernel<<<2048, 256, 0, stream>>>(x2, ln2_g, ln2_b, h2);
    gemm_bt<2, 24, 8><<<1536, 256, 0, stream>>>(h2, wfc1, fc1_b, a1, nullptr, nullptr, 3072, 768);
    gemm_res64<<<768, 256, 0, stream>>>(a1, wfc2, fc2_b, x2, (float*)d_out, 768, 3072);
}

// Round 9
// 388.831 us; speedup vs baseline: 1.1224x; 1.1224x over previous
//
#include <hip/hip_runtime.h>
#include <cstdint>

typedef __bf16 bf16_t;
typedef __attribute__((ext_vector_type(8))) __bf16 bf16x8;
typedef __attribute__((ext_vector_type(4))) __bf16 bf16x4;
typedef __attribute__((ext_vector_type(4))) float f32x4;

#define MFMA16(a, b, c) __builtin_amdgcn_mfma_f32_16x16x32_bf16((a), (b), (c), 0, 0, 0)

// async global->LDS, 16B per lane. LDS dest must be wave-uniform base; HW writes lane i at base + i*16.
__device__ inline void gll16(const bf16_t* g, bf16_t* lds) {
    __builtin_amdgcn_global_load_lds(
        (const __attribute__((address_space(1))) uint32_t*)g,
        (__attribute__((address_space(3))) uint32_t*)lds, 16, 0, 0);
}

// fast GELU: tanh form, exp2-domain. max dev from exact erf-GELU ~5e-4.
__device__ inline float gelu_f(float v) {
    const float u = v + 0.044715f * v * v * v;
    return v / (1.0f + exp2f(-2.3022038f * u));
}

// ---------------- fp32 -> bf16 convert, all 4 weights in one launch ----------------
__global__ __launch_bounds__(256) void cvt4_kernel(const float* __restrict__ s0, bf16_t* __restrict__ d0,
                                                   const float* __restrict__ s1, bf16_t* __restrict__ d1,
                                                   const float* __restrict__ s2, bf16_t* __restrict__ d2,
                                                   const float* __restrict__ s3, bf16_t* __restrict__ d3) {
    const int blk = blockIdx.x;
    const float* s; bf16_t* d; int base;
    if (blk < 864)       { s = s0; d = d0; base = blk; }
    else if (blk < 1152) { s = s1; d = d1; base = blk - 864; }
    else if (blk < 2304) { s = s2; d = d2; base = blk - 1152; }
    else                 { s = s3; d = d3; base = blk - 2304; }
    const int i = (base * 256 + threadIdx.x) * 8;
    const float4* sp = (const float4*)(s + i);
    float4 a = sp[0], b = sp[1];
    bf16x8 o;
    o[0] = (bf16_t)a.x; o[1] = (bf16_t)a.y; o[2] = (bf16_t)a.z; o[3] = (bf16_t)a.w;
    o[4] = (bf16_t)b.x; o[5] = (bf16_t)b.y; o[6] = (bf16_t)b.z; o[7] = (bf16_t)b.w;
    *(bf16x8*)(d + i) = o;
}

// ---------------- LayerNorm: wave per row (768 cols), fp32 in -> bf16 out ----------------
__global__ __launch_bounds__(256) void ln_kernel(const float* __restrict__ x,
                                                 const float* __restrict__ gw,
                                                 const float* __restrict__ bw,
                                                 bf16_t* __restrict__ out) {
    const int row  = blockIdx.x * 4 + (threadIdx.x >> 6);
    const int lane = threadIdx.x & 63;
    const float4* xr = (const float4*)(x + (long)row * 768);
    float4 v[3];
    float s = 0.f, q = 0.f;
#pragma unroll
    for (int j = 0; j < 3; ++j) {
        v[j] = xr[j * 64 + lane];
        s += v[j].x + v[j].y + v[j].z + v[j].w;
        q += v[j].x * v[j].x + v[j].y * v[j].y + v[j].z * v[j].z + v[j].w * v[j].w;
    }
#pragma unroll
    for (int off = 32; off > 0; off >>= 1) {
        s += __shfl_xor(s, off);
        q += __shfl_xor(q, off);
    }
    const float mu = s * (1.0f / 768.0f);
    const float rs = rsqrtf(q * (1.0f / 768.0f) - mu * mu + 1e-5f);
#pragma unroll
    for (int j = 0; j < 3; ++j) {
        float4 g4 = ((const float4*)gw)[j * 64 + lane];
        float4 b4 = ((const float4*)bw)[j * 64 + lane];
        bf16x4 o;
        o[0] = (bf16_t)((v[j].x - mu) * rs * g4.x + b4.x);
        o[1] = (bf16_t)((v[j].y - mu) * rs * g4.y + b4.y);
        o[2] = (bf16_t)((v[j].z - mu) * rs * g4.z + b4.z);
        o[3] = (bf16_t)((v[j].w - mu) * rs * g4.w + b4.w);
        *(bf16x4*)(out + (long)row * 768 + (j * 64 + lane) * 4) = o;
    }
}

// ---------------- GEMM 128x128, XCD-swizzled 1D grid ----------------
// MODE 0: QKV split-scatter: q->outb[bh][n][64], k->o1[bh][n][64],
//         v->o2[bh][64][1024'] transposed + KEY-PERMUTED within each 128-token tile:
//         column c = (tok&15)*8 + ((tok>>4)&7)  — makes attn P-writes contiguous.
// MODE 2: out_bf16 = gelu(acc + bias)  (fc1), LDS-transpose epilogue -> bf16x8 stores.
template <int MODE, int NC, int RPX>
__global__ __launch_bounds__(256) void gemm_bt(const bf16_t* __restrict__ A,
                                               const bf16_t* __restrict__ Bw,
                                               const float* __restrict__ bias,
                                               bf16_t* __restrict__ outb,
                                               bf16_t* __restrict__ o1,
                                               bf16_t* __restrict__ o2,
                                               int Nn, int K) {
    __shared__ __align__(16) bf16_t As[128 * 32];
    __shared__ __align__(16) bf16_t Bs[128 * 32];
    __shared__ __align__(16) bf16_t Ts[4 * 16 * 72];   // per-wave transpose slab
    const int id = blockIdx.x;
    const int xcd = id & 7, sblk = id >> 3;
    const int tn = (sblk % NC) * 128;
    const int tm = (xcd * RPX + sblk / NC) * 128;
    const int w = threadIdx.x >> 6, l = threadIdx.x & 63;
    const int quad = l >> 4, r16 = l & 15;
    const int wm = (w >> 1) * 64, wn = (w & 1) * 64;
    f32x4 acc[4][4] = {};
    const bf16_t* ga = A  + (long)(tm + w * 32 + (l >> 2)) * K + (l & 3) * 8;
    const bf16_t* gb = Bw + (long)(tn + w * 32 + (l >> 2)) * K + (l & 3) * 8;
    bf16_t* la = As + w * 1024;
    bf16_t* lb = Bs + w * 1024;

    for (int k0 = 0; k0 < K; k0 += 32) {
        gll16(ga + k0,            la);
        gll16(ga + 16 * K + k0,   la + 512);
        gll16(gb + k0,            lb);
        gll16(gb + 16 * K + k0,   lb + 512);
        __syncthreads();
        bf16x8 af[4], bfr[4];
#pragma unroll
        for (int i = 0; i < 4; ++i) {
            af[i]  = *(const bf16x8*)&As[(wm + i * 16 + r16) * 32 + quad * 8];
            bfr[i] = *(const bf16x8*)&Bs[(wn + i * 16 + r16) * 32 + quad * 8];
        }
#pragma unroll
        for (int i = 0; i < 4; ++i)
#pragma unroll
            for (int j = 0; j < 4; ++j)
                acc[i][j] = MFMA16(af[i], bfr[j], acc[i][j]);
        __syncthreads();
    }

    bf16_t* tw = Ts + w * 16 * 72;
    if (MODE == 0) {
        const int sect = (tn + wn) / 768;               // wave-uniform (64-aligned)
        const int cwb  = tn + wn - sect * 768;
        const int h    = cwb >> 6;                      // wave-uniform head
        if (sect == 2) {
            // V: permuted-transposed scatter (scalar b16; this kernel has latency slack)
#pragma unroll
            for (int i = 0; i < 4; ++i) {
                const int r0 = tm + wm + i * 16 + quad * 4;
                const int b = r0 >> 10, n0 = r0 & 1023;
#pragma unroll
                for (int j = 0; j < 4; ++j) {
                    const int d = j * 16 + r16;
                    const float bv = bias[tn + wn + j * 16 + r16];
                    bf16_t* dst = o2 + ((long)(b * 12 + h) * 64 + d) * 1024;
#pragma unroll
                    for (int rr = 0; rr < 4; ++rr) {
                        const int nn = n0 + rr;
                        const int c = ((nn & 15) << 3) | ((nn >> 4) & 7);
                        dst[(nn & 0x380) + c] = (bf16_t)(acc[i][j][rr] + bv);
                    }
                }
            }
        } else {
            bf16_t* dstbuf = (sect == 0 ? outb : o1);
#pragma unroll
            for (int i = 0; i < 4; ++i) {
#pragma unroll
                for (int j = 0; j < 4; ++j) {
                    const float bv = bias[tn + wn + j * 16 + r16];
#pragma unroll
                    for (int rr = 0; rr < 4; ++rr)
                        tw[(quad * 4 + rr) * 72 + j * 16 + r16] = (bf16_t)(acc[i][j][rr] + bv);
                }
                const int tok = tm + wm + i * 16 + (l >> 2);
                const int b = tok >> 10, n0 = tok & 1023;
                const long base = (long)(b * 12 + h) * 65536 + (long)n0 * 64;
#pragma unroll
                for (int it = 0; it < 2; ++it) {
                    bf16x8 vv = *(const bf16x8*)&tw[(l >> 2) * 72 + (l & 3) * 8 + it * 32];
                    *(bf16x8*)(dstbuf + base + (l & 3) * 8 + it * 32) = vv;
                }
            }
        }
    } else {
        // FC1: gelu -> LDS transpose -> bf16x8 row-major stores
#pragma unroll
        for (int i = 0; i < 4; ++i) {
#pragma unroll
            for (int j = 0; j < 4; ++j) {
                const float bv = bias[tn + wn + j * 16 + r16];
#pragma unroll
                for (int rr = 0; rr < 4; ++rr)
                    tw[(quad * 4 + rr) * 72 + j * 16 + r16] = (bf16_t)gelu_f(acc[i][j][rr] + bv);
            }
            const int grow = tm + wm + i * 16 + (l >> 2);
#pragma unroll
            for (int it = 0; it < 2; ++it) {
                bf16x8 vv = *(const bf16x8*)&tw[(l >> 2) * 72 + (l & 3) * 8 + it * 32];
                *(bf16x8*)(outb + (long)grow * Nn + tn + wn + (l & 3) * 8 + it * 32) = vv;
            }
        }
    }
}

// ---------------- GEMM 64x128 + residual (proj / fc2), XCD-swizzled 1D grid ----------------
__global__ __launch_bounds__(256) void gemm_res64(const bf16_t* __restrict__ A,
                                                  const bf16_t* __restrict__ Bw,
                                                  const float* __restrict__ bias,
                                                  const float* __restrict__ res,
                                                  float* __restrict__ outf,
                                                  int Nn, int K) {
    __shared__ __align__(16) bf16_t As[64 * 32];
    __shared__ __align__(16) bf16_t Bs[128 * 32];
    __shared__ __align__(16) float  Tf[4 * 16 * 68];   // per-wave fp32 transpose slab
    const int id = blockIdx.x;
    const int xcd = id & 7, sblk = id >> 3;
    const int tn = (sblk % 6) * 128;
    const int tm = (xcd * 16 + sblk / 6) * 64;
    const int w = threadIdx.x >> 6, l = threadIdx.x & 63;
    const int quad = l >> 4, r16 = l & 15;
    const int wm = (w >> 1) * 32, wn = (w & 1) * 64;
    f32x4 acc[2][4] = {};
    const bf16_t* ga = A  + (long)(tm + w * 16 + (l >> 2)) * K + (l & 3) * 8;
    const bf16_t* gb = Bw + (long)(tn + w * 32 + (l >> 2)) * K + (l & 3) * 8;
    bf16_t* la = As + w * 512;
    bf16_t* lb = Bs + w * 1024;

    for (int k0 = 0; k0 < K; k0 += 32) {
        gll16(ga + k0,            la);
        gll16(gb + k0,            lb);
        gll16(gb + 16 * K + k0,   lb + 512);
        __syncthreads();
        bf16x8 af[2], bfr[4];
#pragma unroll
        for (int i = 0; i < 2; ++i)
            af[i]  = *(const bf16x8*)&As[(wm + i * 16 + r16) * 32 + quad * 8];
#pragma unroll
        for (int j = 0; j < 4; ++j)
            bfr[j] = *(const bf16x8*)&Bs[(wn + j * 16 + r16) * 32 + quad * 8];
#pragma unroll
        for (int i = 0; i < 2; ++i)
#pragma unroll
            for (int j = 0; j < 4; ++j)
                acc[i][j] = MFMA16(af[i], bfr[j], acc[i][j]);
        __syncthreads();
    }
    float* tf = Tf + w * 16 * 68;
#pragma unroll
    for (int i = 0; i < 2; ++i) {
#pragma unroll
        for (int j = 0; j < 4; ++j) {
            const float bv = bias[tn + wn + j * 16 + r16];
#pragma unroll
            for (int rr = 0; rr < 4; ++rr)
                tf[(quad * 4 + rr) * 68 + j * 16 + r16] = acc[i][j][rr] + bv;
        }
        const int grow = tm + wm + i * 16 + (l >> 2);
#pragma unroll
        for (int it = 0; it < 4; ++it) {
            const int gcol = tn + wn + (l & 3) * 4 + it * 16;
            f32x4 vv = *(const f32x4*)&tf[(l >> 2) * 68 + (l & 3) * 4 + it * 16];
            const float4 rv = *(const float4*)(res + (long)grow * Nn + gcol);
            float4 ov;
            ov.x = rv.x + vv[0]; ov.y = rv.y + vv[1];
            ov.z = rv.z + vv[2]; ov.w = rv.w + vv[3];
            *(float4*)(outf + (long)grow * Nn + gcol) = ov;
        }
    }
}

// ---------------- Flash attention: K-tile 128 (r7 base) + reg-prefetch + vector P-writes ----------
// grid (96 bh, 8 qt): XCD = bh%8, per-head K/V L2-resident. block 256 = 4 waves, wave = 32 q-rows.
// Keys within each 128-tile are PERMUTED (c = (k&15)*8 + (k>>4)); vtb is written pre-permuted by
// the QKV epilogue, so P-writes become bf16x8 and PV is consistent. Softmax is permutation-invariant.
__global__ __launch_bounds__(256, 3) void attn_kernel(const bf16_t* __restrict__ qh,
                                                      const bf16_t* __restrict__ kh,
                                                      const bf16_t* __restrict__ vt,
                                                      bf16_t* __restrict__ ctx) {
    __shared__ __align__(16) bf16_t Ks[128 * 72];     // K-tile [key][d], pad 72
    __shared__ __align__(16) bf16_t Vt[64 * 136];     // V^T-tile [d][c], pad 136 (permuted cols)
    __shared__ __align__(16) bf16_t Ps[4 * 16 * 136]; // per-wave P buffer [16 q][c]
    const int w = threadIdx.x >> 6, l = threadIdx.x & 63;
    const int quad = l >> 4, r16 = l & 15;
    const int bh = blockIdx.x, qt = blockIdx.y;
    const bf16_t* qp = qh + (long)bh * 65536;
    const bf16_t* kp = kh + (long)bh * 65536;
    const bf16_t* vp = vt + (long)bh * 65536;
    const int q0 = qt * 128 + w * 32;
    const float SC = 0.18033688011f;  // (1/8) * log2(e): softmax in exp2 domain

    bf16x8 qf[2][2];
#pragma unroll
    for (int mt = 0; mt < 2; ++mt)
#pragma unroll
        for (int kq = 0; kq < 2; ++kq)
            qf[mt][kq] = *(const bf16x8*)(qp + (long)(q0 + mt * 16 + r16) * 64 + kq * 32 + quad * 8);

    float lsum[2][4] = {};   // per-lane partial row sums (16 lanes of a quad share rows)
    f32x4 oacc[2][4] = {};
    bf16_t* pw = Ps + w * 16 * 136;

    // register prefetch of K/V staging (tile kt+1 loaded during tile kt compute)
    bf16x8 kpre[4], vpre[4];
#pragma unroll
    for (int c = 0; c < 4; ++c) {
        const int cc = threadIdx.x + c * 256;
        kpre[c] = *(const bf16x8*)(kp + (long)(cc >> 3) * 64 + (cc & 7) * 8);
        vpre[c] = *(const bf16x8*)(vp + (long)(cc >> 4) * 1024 + (cc & 15) * 8);
    }

    for (int kt = 0; kt < 8; ++kt) {
        __syncthreads();    // all waves done reading LDS of tile kt-1
#pragma unroll
        for (int c = 0; c < 4; ++c) {
            const int cc = threadIdx.x + c * 256;
            *(bf16x8*)&Ks[(cc >> 3) * 72 + (cc & 7) * 8] = kpre[c];
            *(bf16x8*)&Vt[(cc >> 4) * 136 + (cc & 15) * 8] = vpre[c];
        }
        __syncthreads();
        if (kt < 7) {
            const int kb = (kt + 1) * 128;
#pragma unroll
            for (int c = 0; c < 4; ++c) {
                const int cc = threadIdx.x + c * 256;
                kpre[c] = *(const bf16x8*)(kp + (long)(kb + (cc >> 3)) * 64 + (cc & 7) * 8);
                vpre[c] = *(const bf16x8*)(vp + (long)(cc >> 4) * 1024 + kb + (cc & 15) * 8);
            }
        }

#pragma unroll
        for (int mt = 0; mt < 2; ++mt) {
            f32x4 s[8] = {};
#pragma unroll
            for (int nt = 0; nt < 8; ++nt) {
                bf16x8 kf0 = *(const bf16x8*)&Ks[(nt * 16 + r16) * 72 + quad * 8];
                bf16x8 kf1 = *(const bf16x8*)&Ks[(nt * 16 + r16) * 72 + 32 + quad * 8];
                s[nt] = MFMA16(qf[mt][0], kf0, s[nt]);
                s[nt] = MFMA16(qf[mt][1], kf1, s[nt]);
            }
            // p = exp2(s*SC); P-write VECTORIZED: row q = quad*4+rr, col c = r16*8+nt
            // (value for key nt*16+r16 lands at c with inv(c) = (c&7)*16 + (c>>3))
#pragma unroll
            for (int rr = 0; rr < 4; ++rr) {
                bf16x8 pv;
#pragma unroll
                for (int nt = 0; nt < 8; ++nt) {
                    const float p = exp2f(s[nt][rr] * SC);
                    lsum[mt][rr] += p;
                    pv[nt] = (bf16_t)p;
                }
                *(bf16x8*)&pw[(quad * 4 + rr) * 136 + r16 * 8] = pv;
            }
            // O += P V  (both operands in permuted-c order; sum over c == sum over keys)
#pragma unroll
            for (int kc = 0; kc < 4; ++kc) {
                bf16x8 pf = *(const bf16x8*)&pw[r16 * 136 + kc * 32 + quad * 8];
#pragma unroll
                for (int dt = 0; dt < 4; ++dt) {
                    bf16x8 vf = *(const bf16x8*)&Vt[(dt * 16 + r16) * 136 + kc * 32 + quad * 8];
                    oacc[mt][dt] = MFMA16(pf, vf, oacc[mt][dt]);
                }
            }
        }
        // no trailing barrier: loop-top barrier protects LDS reuse
    }
#pragma unroll
    for (int mt = 0; mt < 2; ++mt)
#pragma unroll
        for (int rr = 0; rr < 4; ++rr) {
#pragma unroll
            for (int off = 1; off < 16; off <<= 1)
                lsum[mt][rr] += __shfl_xor(lsum[mt][rr], off);
        }
    // epilogue: O/l -> per-wave LDS slab [16 tok][72] (reuse Ps) -> bf16x8 stores.
    // 16 tokens/tile, 4 lanes per token (row = l>>2, 16 elems/lane). same-wave DS ordering.
    const int b = bh / 12, h = bh % 12;
    const long tb = (long)b * 1024;
#pragma unroll
    for (int mt = 0; mt < 2; ++mt) {
#pragma unroll
        for (int dt = 0; dt < 4; ++dt)
#pragma unroll
            for (int rr = 0; rr < 4; ++rr)
                pw[(quad * 4 + rr) * 72 + dt * 16 + r16] =
                    (bf16_t)(oacc[mt][dt][rr] / lsum[mt][rr]);
        const int tok = q0 + mt * 16 + (l >> 2);
        const int off = (l & 3) * 16;
        bf16_t* dst = ctx + (tb + tok) * 768 + h * 64 + off;
        const bf16_t* src = &pw[(l >> 2) * 72 + off];
#pragma unroll
        for (int it = 0; it < 2; ++it)
            *(bf16x8*)(dst + it * 8) = *(const bf16x8*)(src + it * 8);
    }
}

// ---------------- launch ----------------
extern "C" void kernel_launch(void* const* d_in, const int* in_sizes, int n_in,
                              void* d_out, int out_size, void* d_ws, size_t ws_size,
                              hipStream_t stream) {
    const float* x      = (const float*)d_in[0];
    const float* ln1_g  = (const float*)d_in[1];
    const float* ln1_b  = (const float*)d_in[2];
    const float* qkv_w  = (const float*)d_in[3];
    const float* qkv_b  = (const float*)d_in[4];
    const float* proj_w = (const float*)d_in[5];
    const float* proj_b = (const float*)d_in[6];
    const float* ln2_g  = (const float*)d_in[7];
    const float* ln2_b  = (const float*)d_in[8];
    const float* fc1_w  = (const float*)d_in[9];
    const float* fc1_b  = (const float*)d_in[10];
    const float* fc2_w  = (const float*)d_in[11];
    const float* fc2_b  = (const float*)d_in[12];

    char* p = (char*)d_ws;
    bf16_t* wqkv  = (bf16_t*)p; p += (size_t)2304 * 768 * 2;
    bf16_t* wproj = (bf16_t*)p; p += (size_t)768 * 768 * 2;
    bf16_t* wfc1  = (bf16_t*)p; p += (size_t)3072 * 768 * 2;
    bf16_t* wfc2  = (bf16_t*)p; p += (size_t)768 * 3072 * 2;
    bf16_t* h1    = (bf16_t*)p; p += (size_t)8192 * 768 * 2;
    bf16_t* qhb   = (bf16_t*)p; p += (size_t)96 * 1024 * 64 * 2;
    bf16_t* khb   = (bf16_t*)p; p += (size_t)96 * 1024 * 64 * 2;
    bf16_t* vtb   = (bf16_t*)p; p += (size_t)96 * 64 * 1024 * 2;
    bf16_t* ctx   = (bf16_t*)p; p += (size_t)8192 * 768 * 2;
    float*  x2    = (float*)p;  p += (size_t)8192 * 768 * 4;
    bf16_t* h2    = (bf16_t*)p; p += (size_t)8192 * 768 * 2;
    bf16_t* a1    = (bf16_t*)p; p += (size_t)8192 * 3072 * 2;

    cvt4_kernel<<<3456, 256, 0, stream>>>(qkv_w, wqkv, proj_w, wproj, fc1_w, wfc1, fc2_w, wfc2);

    ln_kernel<<<2048, 256, 0, stream>>>(x, ln1_g, ln1_b, h1);
    gemm_bt<0, 18, 8><<<1152, 256, 0, stream>>>(h1, wqkv, qkv_b, qhb, khb, vtb, 2304, 768);
    attn_kernel<<<dim3(96, 8), 256, 0, stream>>>(qhb, khb, vtb, ctx);
    gemm_res64<<<768, 256, 0, stream>>>(ctx, wproj, proj_b, x, x2, 768, 768);
    ln_kernel<<<2048, 256, 0, stream>>>(x2, ln2_g, ln2_b, h2);
    gemm_bt<2, 24, 8><<<1536, 256, 0, stream>>>(h2, wfc1, fc1_b, a1, nullptr, nullptr, 3072, 768);
    gemm_res64<<<768, 256, 0, stream>>>(a1, wfc2, fc2_b, x2, (float*)d_out, 768, 3072);
}

// Round 10
// 374.988 us; speedup vs baseline: 1.1639x; 1.0369x over previous
//
#include <hip/hip_runtime.h>
#include <cstdint>

typedef __bf16 bf16_t;
typedef __attribute__((ext_vector_type(8))) __bf16 bf16x8;
typedef __attribute__((ext_vector_type(4))) __bf16 bf16x4;
typedef __attribute__((ext_vector_type(4))) float f32x4;

#define MFMA16(a, b, c) __builtin_amdgcn_mfma_f32_16x16x32_bf16((a), (b), (c), 0, 0, 0)

// fast GELU: tanh form, exp2-domain. max dev from exact erf-GELU ~5e-4.
__device__ inline float gelu_f(float v) {
    const float u = v + 0.044715f * v * v * v;
    return v / (1.0f + exp2f(-2.3022038f * u));
}

// ---------------- fp32 -> bf16 convert, all 4 weights in one launch ----------------
__global__ __launch_bounds__(256) void cvt4_kernel(const float* __restrict__ s0, bf16_t* __restrict__ d0,
                                                   const float* __restrict__ s1, bf16_t* __restrict__ d1,
                                                   const float* __restrict__ s2, bf16_t* __restrict__ d2,
                                                   const float* __restrict__ s3, bf16_t* __restrict__ d3) {
    const int blk = blockIdx.x;
    const float* s; bf16_t* d; int base;
    if (blk < 864)       { s = s0; d = d0; base = blk; }
    else if (blk < 1152) { s = s1; d = d1; base = blk - 864; }
    else if (blk < 2304) { s = s2; d = d2; base = blk - 1152; }
    else                 { s = s3; d = d3; base = blk - 2304; }
    const int i = (base * 256 + threadIdx.x) * 8;
    const float4* sp = (const float4*)(s + i);
    float4 a = sp[0], b = sp[1];
    bf16x8 o;
    o[0] = (bf16_t)a.x; o[1] = (bf16_t)a.y; o[2] = (bf16_t)a.z; o[3] = (bf16_t)a.w;
    o[4] = (bf16_t)b.x; o[5] = (bf16_t)b.y; o[6] = (bf16_t)b.z; o[7] = (bf16_t)b.w;
    *(bf16x8*)(d + i) = o;
}

// ---------------- LayerNorm: wave per row (768 cols), fp32 in -> bf16 out ----------------
__global__ __launch_bounds__(256) void ln_kernel(const float* __restrict__ x,
                                                 const float* __restrict__ gw,
                                                 const float* __restrict__ bw,
                                                 bf16_t* __restrict__ out) {
    const int row  = blockIdx.x * 4 + (threadIdx.x >> 6);
    const int lane = threadIdx.x & 63;
    const float4* xr = (const float4*)(x + (long)row * 768);
    float4 v[3];
    float s = 0.f, q = 0.f;
#pragma unroll
    for (int j = 0; j < 3; ++j) {
        v[j] = xr[j * 64 + lane];
        s += v[j].x + v[j].y + v[j].z + v[j].w;
        q += v[j].x * v[j].x + v[j].y * v[j].y + v[j].z * v[j].z + v[j].w * v[j].w;
    }
#pragma unroll
    for (int off = 32; off > 0; off >>= 1) {
        s += __shfl_xor(s, off);
        q += __shfl_xor(q, off);
    }
    const float mu = s * (1.0f / 768.0f);
    const float rs = rsqrtf(q * (1.0f / 768.0f) - mu * mu + 1e-5f);
#pragma unroll
    for (int j = 0; j < 3; ++j) {
        float4 g4 = ((const float4*)gw)[j * 64 + lane];
        float4 b4 = ((const float4*)bw)[j * 64 + lane];
        bf16x4 o;
        o[0] = (bf16_t)((v[j].x - mu) * rs * g4.x + b4.x);
        o[1] = (bf16_t)((v[j].y - mu) * rs * g4.y + b4.y);
        o[2] = (bf16_t)((v[j].z - mu) * rs * g4.z + b4.z);
        o[3] = (bf16_t)((v[j].w - mu) * rs * g4.w + b4.w);
        *(bf16x4*)(out + (long)row * 768 + (j * 64 + lane) * 4) = o;
    }
}

// ---------------- GEMM 128x128, XCD-swizzled 1D grid, register-prefetch staging ----------------
// K-loop: ds_write tile k from regs -> barrier -> issue loads for k+1 -> compute k.
// VMEM latency overlaps the compute of the current tile; barrier waits on lgkm only.
// MODE 0: QKV split-scatter: q->outb[bh][n][64], k->o1[bh][n][64],
//         v->o2[bh][64][1024'] transposed + KEY-PERMUTED (c = (tok&15)*8 + ((tok>>4)&7)).
// MODE 2: out_bf16 = gelu(acc + bias)  (fc1), LDS-transpose epilogue -> bf16x8 stores.
template <int MODE, int NC, int RPX>
__global__ __launch_bounds__(256) void gemm_bt(const bf16_t* __restrict__ A,
                                               const bf16_t* __restrict__ Bw,
                                               const float* __restrict__ bias,
                                               bf16_t* __restrict__ outb,
                                               bf16_t* __restrict__ o1,
                                               bf16_t* __restrict__ o2,
                                               int Nn, int K) {
    __shared__ __align__(16) bf16_t As[128 * 32];
    __shared__ __align__(16) bf16_t Bs[128 * 32];
    __shared__ __align__(16) bf16_t Ts[4 * 16 * 72];   // per-wave transpose slab
    const int id = blockIdx.x;
    const int xcd = id & 7, sblk = id >> 3;
    const int tn = (sblk % NC) * 128;
    const int tm = (xcd * RPX + sblk / NC) * 128;
    const int w = threadIdx.x >> 6, l = threadIdx.x & 63;
    const int quad = l >> 4, r16 = l & 15;
    const int wm = (w >> 1) * 64, wn = (w & 1) * 64;
    f32x4 acc[4][4] = {};
    const bf16_t* ga = A  + (long)(tm + w * 32 + (l >> 2)) * K + (l & 3) * 8;
    const bf16_t* gb = Bw + (long)(tn + w * 32 + (l >> 2)) * K + (l & 3) * 8;
    bf16_t* la = As + w * 1024;
    bf16_t* lb = Bs + w * 1024;

    // prologue: tile 0 into regs
    bf16x8 pa0 = *(const bf16x8*)(ga);
    bf16x8 pa1 = *(const bf16x8*)(ga + 16 * K);
    bf16x8 pb0 = *(const bf16x8*)(gb);
    bf16x8 pb1 = *(const bf16x8*)(gb + 16 * K);

    for (int k0 = 0; k0 < K; k0 += 32) {
        __syncthreads();           // all waves done reading previous tile's LDS
        *(bf16x8*)(la + l * 8)       = pa0;
        *(bf16x8*)(la + 512 + l * 8) = pa1;
        *(bf16x8*)(lb + l * 8)       = pb0;
        *(bf16x8*)(lb + 512 + l * 8) = pb1;
        __syncthreads();
        if (k0 + 32 < K) {         // issue next-tile loads before compute
            pa0 = *(const bf16x8*)(ga + k0 + 32);
            pa1 = *(const bf16x8*)(ga + 16 * K + k0 + 32);
            pb0 = *(const bf16x8*)(gb + k0 + 32);
            pb1 = *(const bf16x8*)(gb + 16 * K + k0 + 32);
        }
        bf16x8 af[4], bfr[4];
#pragma unroll
        for (int i = 0; i < 4; ++i) {
            af[i]  = *(const bf16x8*)&As[(wm + i * 16 + r16) * 32 + quad * 8];
            bfr[i] = *(const bf16x8*)&Bs[(wn + i * 16 + r16) * 32 + quad * 8];
        }
#pragma unroll
        for (int i = 0; i < 4; ++i)
#pragma unroll
            for (int j = 0; j < 4; ++j)
                acc[i][j] = MFMA16(af[i], bfr[j], acc[i][j]);
    }

    bf16_t* tw = Ts + w * 16 * 72;
    if (MODE == 0) {
        const int sect = (tn + wn) / 768;               // wave-uniform (64-aligned)
        const int cwb  = tn + wn - sect * 768;
        const int h    = cwb >> 6;                      // wave-uniform head
        if (sect == 2) {
            // V: permuted-transposed scatter (scalar b16; this kernel has latency slack)
#pragma unroll
            for (int i = 0; i < 4; ++i) {
                const int r0 = tm + wm + i * 16 + quad * 4;
                const int b = r0 >> 10, n0 = r0 & 1023;
#pragma unroll
                for (int j = 0; j < 4; ++j) {
                    const int d = j * 16 + r16;
                    const float bv = bias[tn + wn + j * 16 + r16];
                    bf16_t* dst = o2 + ((long)(b * 12 + h) * 64 + d) * 1024;
#pragma unroll
                    for (int rr = 0; rr < 4; ++rr) {
                        const int nn = n0 + rr;
                        const int c = ((nn & 15) << 3) | ((nn >> 4) & 7);
                        dst[(nn & 0x380) + c] = (bf16_t)(acc[i][j][rr] + bv);
                    }
                }
            }
        } else {
            bf16_t* dstbuf = (sect == 0 ? outb : o1);
#pragma unroll
            for (int i = 0; i < 4; ++i) {
#pragma unroll
                for (int j = 0; j < 4; ++j) {
                    const float bv = bias[tn + wn + j * 16 + r16];
#pragma unroll
                    for (int rr = 0; rr < 4; ++rr)
                        tw[(quad * 4 + rr) * 72 + j * 16 + r16] = (bf16_t)(acc[i][j][rr] + bv);
                }
                const int tok = tm + wm + i * 16 + (l >> 2);
                const int b = tok >> 10, n0 = tok & 1023;
                const long base = (long)(b * 12 + h) * 65536 + (long)n0 * 64;
#pragma unroll
                for (int it = 0; it < 2; ++it) {
                    bf16x8 vv = *(const bf16x8*)&tw[(l >> 2) * 72 + (l & 3) * 8 + it * 32];
                    *(bf16x8*)(dstbuf + base + (l & 3) * 8 + it * 32) = vv;
                }
            }
        }
    } else {
        // FC1: gelu -> LDS transpose -> bf16x8 row-major stores
#pragma unroll
        for (int i = 0; i < 4; ++i) {
#pragma unroll
            for (int j = 0; j < 4; ++j) {
                const float bv = bias[tn + wn + j * 16 + r16];
#pragma unroll
                for (int rr = 0; rr < 4; ++rr)
                    tw[(quad * 4 + rr) * 72 + j * 16 + r16] = (bf16_t)gelu_f(acc[i][j][rr] + bv);
            }
            const int grow = tm + wm + i * 16 + (l >> 2);
#pragma unroll
            for (int it = 0; it < 2; ++it) {
                bf16x8 vv = *(const bf16x8*)&tw[(l >> 2) * 72 + (l & 3) * 8 + it * 32];
                *(bf16x8*)(outb + (long)grow * Nn + tn + wn + (l & 3) * 8 + it * 32) = vv;
            }
        }
    }
}

// ---------------- GEMM 64x128 + residual (proj / fc2), XCD-swizzled, register-prefetch ----------
__global__ __launch_bounds__(256) void gemm_res64(const bf16_t* __restrict__ A,
                                                  const bf16_t* __restrict__ Bw,
                                                  const float* __restrict__ bias,
                                                  const float* __restrict__ res,
                                                  float* __restrict__ outf,
                                                  int Nn, int K) {
    __shared__ __align__(16) bf16_t As[64 * 32];
    __shared__ __align__(16) bf16_t Bs[128 * 32];
    __shared__ __align__(16) float  Tf[4 * 16 * 68];   // per-wave fp32 transpose slab
    const int id = blockIdx.x;
    const int xcd = id & 7, sblk = id >> 3;
    const int tn = (sblk % 6) * 128;
    const int tm = (xcd * 16 + sblk / 6) * 64;
    const int w = threadIdx.x >> 6, l = threadIdx.x & 63;
    const int quad = l >> 4, r16 = l & 15;
    const int wm = (w >> 1) * 32, wn = (w & 1) * 64;
    f32x4 acc[2][4] = {};
    const bf16_t* ga = A  + (long)(tm + w * 16 + (l >> 2)) * K + (l & 3) * 8;
    const bf16_t* gb = Bw + (long)(tn + w * 32 + (l >> 2)) * K + (l & 3) * 8;
    bf16_t* la = As + w * 512;
    bf16_t* lb = Bs + w * 1024;

    bf16x8 pa = *(const bf16x8*)(ga);
    bf16x8 pb0 = *(const bf16x8*)(gb);
    bf16x8 pb1 = *(const bf16x8*)(gb + 16 * K);

    for (int k0 = 0; k0 < K; k0 += 32) {
        __syncthreads();
        *(bf16x8*)(la + l * 8)       = pa;
        *(bf16x8*)(lb + l * 8)       = pb0;
        *(bf16x8*)(lb + 512 + l * 8) = pb1;
        __syncthreads();
        if (k0 + 32 < K) {
            pa  = *(const bf16x8*)(ga + k0 + 32);
            pb0 = *(const bf16x8*)(gb + k0 + 32);
            pb1 = *(const bf16x8*)(gb + 16 * K + k0 + 32);
        }
        bf16x8 af[2], bfr[4];
#pragma unroll
        for (int i = 0; i < 2; ++i)
            af[i]  = *(const bf16x8*)&As[(wm + i * 16 + r16) * 32 + quad * 8];
#pragma unroll
        for (int j = 0; j < 4; ++j)
            bfr[j] = *(const bf16x8*)&Bs[(wn + j * 16 + r16) * 32 + quad * 8];
#pragma unroll
        for (int i = 0; i < 2; ++i)
#pragma unroll
            for (int j = 0; j < 4; ++j)
                acc[i][j] = MFMA16(af[i], bfr[j], acc[i][j]);
    }
    float* tf = Tf + w * 16 * 68;
#pragma unroll
    for (int i = 0; i < 2; ++i) {
#pragma unroll
        for (int j = 0; j < 4; ++j) {
            const float bv = bias[tn + wn + j * 16 + r16];
#pragma unroll
            for (int rr = 0; rr < 4; ++rr)
                tf[(quad * 4 + rr) * 68 + j * 16 + r16] = acc[i][j][rr] + bv;
        }
        const int grow = tm + wm + i * 16 + (l >> 2);
#pragma unroll
        for (int it = 0; it < 4; ++it) {
            const int gcol = tn + wn + (l & 3) * 4 + it * 16;
            f32x4 vv = *(const f32x4*)&tf[(l >> 2) * 68 + (l & 3) * 4 + it * 16];
            const float4 rv = *(const float4*)(res + (long)grow * Nn + gcol);
            float4 ov;
            ov.x = rv.x + vv[0]; ov.y = rv.y + vv[1];
            ov.z = rv.z + vv[2]; ov.w = rv.w + vv[3];
            *(float4*)(outf + (long)grow * Nn + gcol) = ov;
        }
    }
}

// ---------------- Flash attention: K-tile 128 + reg-prefetch + vector P-writes (r9) ----------
// grid (96 bh, 8 qt): XCD = bh%8, per-head K/V L2-resident. block 256 = 4 waves, wave = 32 q-rows.
// Keys within each 128-tile are PERMUTED (c = (k&15)*8 + (k>>4)); vtb is written pre-permuted by
// the QKV epilogue, so P-writes become bf16x8 and PV is consistent. Softmax is permutation-invariant.
__global__ __launch_bounds__(256, 3) void attn_kernel(const bf16_t* __restrict__ qh,
                                                      const bf16_t* __restrict__ kh,
                                                      const bf16_t* __restrict__ vt,
                                                      bf16_t* __restrict__ ctx) {
    __shared__ __align__(16) bf16_t Ks[128 * 72];     // K-tile [key][d], pad 72
    __shared__ __align__(16) bf16_t Vt[64 * 136];     // V^T-tile [d][c], pad 136 (permuted cols)
    __shared__ __align__(16) bf16_t Ps[4 * 16 * 136]; // per-wave P buffer [16 q][c]
    const int w = threadIdx.x >> 6, l = threadIdx.x & 63;
    const int quad = l >> 4, r16 = l & 15;
    const int bh = blockIdx.x, qt = blockIdx.y;
    const bf16_t* qp = qh + (long)bh * 65536;
    const bf16_t* kp = kh + (long)bh * 65536;
    const bf16_t* vp = vt + (long)bh * 65536;
    const int q0 = qt * 128 + w * 32;
    const float SC = 0.18033688011f;  // (1/8) * log2(e): softmax in exp2 domain

    bf16x8 qf[2][2];
#pragma unroll
    for (int mt = 0; mt < 2; ++mt)
#pragma unroll
        for (int kq = 0; kq < 2; ++kq)
            qf[mt][kq] = *(const bf16x8*)(qp + (long)(q0 + mt * 16 + r16) * 64 + kq * 32 + quad * 8);

    float lsum[2][4] = {};   // per-lane partial row sums (16 lanes of a quad share rows)
    f32x4 oacc[2][4] = {};
    bf16_t* pw = Ps + w * 16 * 136;

    // register prefetch of K/V staging (tile kt+1 loaded during tile kt compute)
    bf16x8 kpre[4], vpre[4];
#pragma unroll
    for (int c = 0; c < 4; ++c) {
        const int cc = threadIdx.x + c * 256;
        kpre[c] = *(const bf16x8*)(kp + (long)(cc >> 3) * 64 + (cc & 7) * 8);
        vpre[c] = *(const bf16x8*)(vp + (long)(cc >> 4) * 1024 + (cc & 15) * 8);
    }

    for (int kt = 0; kt < 8; ++kt) {
        __syncthreads();    // all waves done reading LDS of tile kt-1
#pragma unroll
        for (int c = 0; c < 4; ++c) {
            const int cc = threadIdx.x + c * 256;
            *(bf16x8*)&Ks[(cc >> 3) * 72 + (cc & 7) * 8] = kpre[c];
            *(bf16x8*)&Vt[(cc >> 4) * 136 + (cc & 15) * 8] = vpre[c];
        }
        __syncthreads();
        if (kt < 7) {
            const int kb = (kt + 1) * 128;
#pragma unroll
            for (int c = 0; c < 4; ++c) {
                const int cc = threadIdx.x + c * 256;
                kpre[c] = *(const bf16x8*)(kp + (long)(kb + (cc >> 3)) * 64 + (cc & 7) * 8);
                vpre[c] = *(const bf16x8*)(vp + (long)(cc >> 4) * 1024 + kb + (cc & 15) * 8);
            }
        }

#pragma unroll
        for (int mt = 0; mt < 2; ++mt) {
            f32x4 s[8] = {};
#pragma unroll
            for (int nt = 0; nt < 8; ++nt) {
                bf16x8 kf0 = *(const bf16x8*)&Ks[(nt * 16 + r16) * 72 + quad * 8];
                bf16x8 kf1 = *(const bf16x8*)&Ks[(nt * 16 + r16) * 72 + 32 + quad * 8];
                s[nt] = MFMA16(qf[mt][0], kf0, s[nt]);
                s[nt] = MFMA16(qf[mt][1], kf1, s[nt]);
            }
            // p = exp2(s*SC); P-write VECTORIZED: row q = quad*4+rr, col c = r16*8+nt
#pragma unroll
            for (int rr = 0; rr < 4; ++rr) {
                bf16x8 pv;
#pragma unroll
                for (int nt = 0; nt < 8; ++nt) {
                    const float p = exp2f(s[nt][rr] * SC);
                    lsum[mt][rr] += p;
                    pv[nt] = (bf16_t)p;
                }
                *(bf16x8*)&pw[(quad * 4 + rr) * 136 + r16 * 8] = pv;
            }
            // O += P V  (both operands in permuted-c order; sum over c == sum over keys)
#pragma unroll
            for (int kc = 0; kc < 4; ++kc) {
                bf16x8 pf = *(const bf16x8*)&pw[r16 * 136 + kc * 32 + quad * 8];
#pragma unroll
                for (int dt = 0; dt < 4; ++dt) {
                    bf16x8 vf = *(const bf16x8*)&Vt[(dt * 16 + r16) * 136 + kc * 32 + quad * 8];
                    oacc[mt][dt] = MFMA16(pf, vf, oacc[mt][dt]);
                }
            }
        }
        // no trailing barrier: loop-top barrier protects LDS reuse
    }
#pragma unroll
    for (int mt = 0; mt < 2; ++mt)
#pragma unroll
        for (int rr = 0; rr < 4; ++rr) {
#pragma unroll
            for (int off = 1; off < 16; off <<= 1)
                lsum[mt][rr] += __shfl_xor(lsum[mt][rr], off);
        }
    // epilogue: O/l -> per-wave LDS slab [16 tok][72] (reuse Ps) -> bf16x8 stores.
    const int b = bh / 12, h = bh % 12;
    const long tb = (long)b * 1024;
#pragma unroll
    for (int mt = 0; mt < 2; ++mt) {
#pragma unroll
        for (int dt = 0; dt < 4; ++dt)
#pragma unroll
            for (int rr = 0; rr < 4; ++rr)
                pw[(quad * 4 + rr) * 72 + dt * 16 + r16] =
                    (bf16_t)(oacc[mt][dt][rr] / lsum[mt][rr]);
        const int tok = q0 + mt * 16 + (l >> 2);
        const int off = (l & 3) * 16;
        bf16_t* dst = ctx + (tb + tok) * 768 + h * 64 + off;
        const bf16_t* src = &pw[(l >> 2) * 72 + off];
#pragma unroll
        for (int it = 0; it < 2; ++it)
            *(bf16x8*)(dst + it * 8) = *(const bf16x8*)(src + it * 8);
    }
}

// ---------------- launch ----------------
extern "C" void kernel_launch(void* const* d_in, const int* in_sizes, int n_in,
                              void* d_out, int out_size, void* d_ws, size_t ws_size,
                              hipStream_t stream) {
    const float* x      = (const float*)d_in[0];
    const float* ln1_g  = (const float*)d_in[1];
    const float* ln1_b  = (const float*)d_in[2];
    const float* qkv_w  = (const float*)d_in[3];
    const float* qkv_b  = (const float*)d_in[4];
    const float* proj_w = (const float*)d_in[5];
    const float* proj_b = (const float*)d_in[6];
    const float* ln2_g  = (const float*)d_in[7];
    const float* ln2_b  = (const float*)d_in[8];
    const float* fc1_w  = (const float*)d_in[9];
    const float* fc1_b  = (const float*)d_in[10];
    const float* fc2_w  = (const float*)d_in[11];
    const float* fc2_b  = (const float*)d_in[12];

    char* p = (char*)d_ws;
    bf16_t* wqkv  = (bf16_t*)p; p += (size_t)2304 * 768 * 2;
    bf16_t* wproj = (bf16_t*)p; p += (size_t)768 * 768 * 2;
    bf16_t* wfc1  = (bf16_t*)p; p += (size_t)3072 * 768 * 2;
    bf16_t* wfc2  = (bf16_t*)p; p += (size_t)768 * 3072 * 2;
    bf16_t* h1    = (bf16_t*)p; p += (size_t)8192 * 768 * 2;
    bf16_t* qhb   = (bf16_t*)p; p += (size_t)96 * 1024 * 64 * 2;
    bf16_t* khb   = (bf16_t*)p; p += (size_t)96 * 1024 * 64 * 2;
    bf16_t* vtb   = (bf16_t*)p; p += (size_t)96 * 64 * 1024 * 2;
    bf16_t* ctx   = (bf16_t*)p; p += (size_t)8192 * 768 * 2;
    float*  x2    = (float*)p;  p += (size_t)8192 * 768 * 4;
    bf16_t* h2    = (bf16_t*)p; p += (size_t)8192 * 768 * 2;
    bf16_t* a1    = (bf16_t*)p; p += (size_t)8192 * 3072 * 2;

    cvt4_kernel<<<3456, 256, 0, stream>>>(qkv_w, wqkv, proj_w, wproj, fc1_w, wfc1, fc2_w, wfc2);

    ln_kernel<<<2048, 256, 0, stream>>>(x, ln1_g, ln1_b, h1);
    gemm_bt<0, 18, 8><<<1152, 256, 0, stream>>>(h1, wqkv, qkv_b, qhb, khb, vtb, 2304, 768);
    attn_kernel<<<dim3(96, 8), 256, 0, stream>>>(qhb, khb, vtb, ctx);
    gemm_res64<<<768, 256, 0, stream>>>(ctx, wproj, proj_b, x, x2, 768, 768);
    ln_kernel<<<2048, 256, 0, stream>>>(x2, ln2_g, ln2_b, h2);
    gemm_bt<2, 24, 8><<<1536, 256, 0, stream>>>(h2, wfc1, fc1_b, a1, nullptr, nullptr, 3072, 768);
    gemm_res64<<<768, 256, 0, stream>>>(a1, wfc2, fc2_b, x2, (float*)d_out, 768, 3072);
}